// Round 2
// baseline (791.069 us; speedup 1.0000x reference)
//
#include <hip/hip_runtime.h>
#include <hip/hip_bf16.h>

typedef unsigned int uint;

#define BATCH 32
#define NCH   256
#define HW    16384

// ---------------------------------------------------------------------------
// Kernel 1: fused spatial pool, single pass over x (512 MiB fp32).
// e_n = exp(<x[:,n],w>+b) accumulated UNNORMALIZED (|logit| <~ 4, exp safe in
// fp32): ctxnum[b,c] = sum_n x[b,c,n]*e_n, zbuf[b] = sum_n e_n via fp32
// atomics; the division happens in the tail kernel.
//
// Grid: 32 b x 64 blocks; each block owns 256 n, processed as 4 chunks of 64.
// Thread (r = tid>>3, m = tid&7) loads an 8c x 8n register slice per chunk
// (c = it*32+r, n = n0+m*8..+7), contributes logit partials from registers,
// then after the LDS logit reduction reuses the SAME registers for the
// context accumulation — x is touched exactly once, no LDS data tile.
// part[] pitch 65: banks hit <=2-way on both write and read (free, m136).
// ---------------------------------------------------------------------------
__global__ __launch_bounds__(256) void spool_kernel(
    const float* __restrict__ x, const float* __restrict__ mask_w,
    const float* __restrict__ mask_b, float* __restrict__ ctxnum,
    float* __restrict__ zbuf)
{
    __shared__ float wlds[NCH];
    __shared__ float part[32 * 65];   // logit partials [r][n_local]
    __shared__ float earr[64];        // exp(logit) for the chunk

    const int tid = threadIdx.x;
    const int b   = blockIdx.x >> 6;
    const int blk = blockIdx.x & 63;
    const int r   = tid >> 3;         // 0..31: c within a 32-row group
    const int m   = tid & 7;          // 0..7 : n-octet

    wlds[tid] = mask_w[tid];
    const float mb = mask_b[0];
    __syncthreads();

    float acc[8] = {0.f,0.f,0.f,0.f,0.f,0.f,0.f,0.f}; // ctx partial per it
    float zacc = 0.f;                                  // valid on tid==0

    const float* xb = x + ((size_t)b << 22) + ((size_t)r << 14) + (m << 3);

    for (int g = 0; g < 4; ++g) {
        const int n0 = (blk << 8) + (g << 6);

        // ---- Phase A: global->registers + logit partials ----
        float4 d0[8], d1[8];
        float la[8] = {0.f,0.f,0.f,0.f,0.f,0.f,0.f,0.f};
        #pragma unroll
        for (int it = 0; it < 8; ++it) {
            const float4* p = (const float4*)(xb + ((size_t)it << 19) + n0);
            d0[it] = p[0];
            d1[it] = p[1];
            const float wc = wlds[(it << 5) + r];
            la[0] += wc * d0[it].x; la[1] += wc * d0[it].y;
            la[2] += wc * d0[it].z; la[3] += wc * d0[it].w;
            la[4] += wc * d1[it].x; la[5] += wc * d1[it].y;
            la[6] += wc * d1[it].z; la[7] += wc * d1[it].w;
        }
        #pragma unroll
        for (int k = 0; k < 8; ++k) part[r * 65 + (m << 3) + k] = la[k];
        __syncthreads();

        // ---- Phase B: finalize 64 logits, exp, chunk Z (wave 0 only) ----
        if (tid < 64) {
            float l = 0.f;
            #pragma unroll
            for (int rr = 0; rr < 32; ++rr) l += part[rr * 65 + tid];
            const float e = expf(l + mb);
            earr[tid] = e;
            float s = e;
            #pragma unroll
            for (int off = 32; off > 0; off >>= 1) s += __shfl_down(s, off, 64);
            zacc += s;
        }
        __syncthreads();

        // ---- Phase C: context accumulation from the register slice ----
        float el[8];
        #pragma unroll
        for (int j = 0; j < 8; ++j) el[j] = earr[(m << 3) + j];
        #pragma unroll
        for (int it = 0; it < 8; ++it) {
            acc[it] += d0[it].x * el[0] + d0[it].y * el[1]
                     + d0[it].z * el[2] + d0[it].w * el[3]
                     + d1[it].x * el[4] + d1[it].y * el[5]
                     + d1[it].z * el[6] + d1[it].w * el[7];
        }
        __syncthreads();   // part/earr reused next chunk
    }

    // Fold the 8 n-octet lanes (m = low 3 lane bits): butterfly per it, then
    // lane m keeps channel c = m*32 + r. One atomic per (b,c) per block.
    float ctxv = 0.f;
    #pragma unroll
    for (int it = 0; it < 8; ++it) {
        float v = acc[it];
        v += __shfl_xor(v, 1, 64);
        v += __shfl_xor(v, 2, 64);
        v += __shfl_xor(v, 4, 64);
        if (m == it) ctxv = v;
    }
    atomicAdd(&ctxnum[(b << 8) + (m << 5) + r], ctxv);
    if (tid == 0) atomicAdd(&zbuf[b], zacc);
}

// ---------------------------------------------------------------------------
// Kernel 2: everything downstream of context (tiny). One block per batch.
//   ctx = num/Z -> cm1 matvec -> LayerNorm(C) -> ReLU -> cm2 -> sigmoid
//   -> out = ix @ out_w[:,:,2,2]^T + out_b ; att = sigmoid(ix @ att_w^T+att_b)
//   -> d_out = att * out   (fp32)
// ---------------------------------------------------------------------------
__global__ __launch_bounds__(256) void tail_kernel(
    const float* __restrict__ ctxnum, const float* __restrict__ zbuf,
    const float* __restrict__ cm1_w, const float* __restrict__ cm1_b,
    const float* __restrict__ ln_g,  const float* __restrict__ ln_b,
    const float* __restrict__ cm2_w, const float* __restrict__ cm2_b,
    const float* __restrict__ out_w, const float* __restrict__ out_b,
    const float* __restrict__ att_w, const float* __restrict__ att_b,
    float* __restrict__ outp)
{
    const int b = blockIdx.x, t = threadIdx.x;
    __shared__ float v[NCH];
    __shared__ float red[8];

    const float zinv = 1.f / zbuf[b];
    v[t] = ctxnum[(b << 8) + t] * zinv;
    __syncthreads();

    // cm1: h[t] = cm1_w[t,:] . ctx + cm1_b[t]
    float h = cm1_b[t];
    {
        const float4* wr = (const float4*)(cm1_w + ((size_t)t << 8));
        #pragma unroll
        for (int jj = 0; jj < 64; ++jj) {
            const float4 w = wr[jj];
            const int c = jj << 2;
            h += w.x * v[c] + w.y * v[c + 1] + w.z * v[c + 2] + w.w * v[c + 3];
        }
    }

    // LayerNorm over the 256 channels (across threads)
    float s1 = h, s2 = h * h;
    #pragma unroll
    for (int off = 32; off > 0; off >>= 1) {
        s1 += __shfl_down(s1, off, 64);
        s2 += __shfl_down(s2, off, 64);
    }
    if ((t & 63) == 0) { red[t >> 6] = s1; red[4 + (t >> 6)] = s2; }
    __syncthreads();
    const float mu  = (red[0] + red[1] + red[2] + red[3]) * (1.f / 256.f);
    const float ex2 = (red[4] + red[5] + red[6] + red[7]) * (1.f / 256.f);
    const float rs  = rsqrtf(ex2 - mu * mu + 1e-5f);
    float sv = (h - mu) * rs * ln_g[t] + ln_b[t];
    sv = fmaxf(sv, 0.f);
    __syncthreads();
    v[t] = sv;
    __syncthreads();

    // cm2 + sigmoid -> input_x
    float h2 = cm2_b[t];
    {
        const float4* wr = (const float4*)(cm2_w + ((size_t)t << 8));
        #pragma unroll
        for (int jj = 0; jj < 64; ++jj) {
            const float4 w = wr[jj];
            const int c = jj << 2;
            h2 += w.x * v[c] + w.y * v[c + 1] + w.z * v[c + 2] + w.w * v[c + 3];
        }
    }
    const float ix = 1.f / (1.f + expf(-h2));
    __syncthreads();
    v[t] = ix;
    __syncthreads();

    // output_conv: only the center tap of the 5x5 survives on 1x1 spatial
    float o = out_b[t];
    {
        const float* ow = out_w + (size_t)t * 6400 + 12;  // [t, c, 2, 2]
        #pragma unroll 8
        for (int c = 0; c < 256; ++c) o += ow[c * 25] * v[c];
    }

    // att gate
    float a = att_b[t];
    {
        const float4* wr = (const float4*)(att_w + ((size_t)t << 8));
        #pragma unroll
        for (int jj = 0; jj < 64; ++jj) {
            const float4 w = wr[jj];
            const int c = jj << 2;
            a += w.x * v[c] + w.y * v[c + 1] + w.z * v[c + 2] + w.w * v[c + 3];
        }
    }
    a = 1.f / (1.f + expf(-a));

    outp[(b << 8) + t] = a * o;
}

extern "C" void kernel_launch(void* const* d_in, const int* in_sizes, int n_in,
                              void* d_out, int out_size, void* d_ws, size_t ws_size,
                              hipStream_t stream) {
    (void)in_sizes; (void)n_in; (void)out_size; (void)ws_size;
    const float* x      = (const float*)d_in[0];
    const float* mask_w = (const float*)d_in[1];
    const float* mask_b = (const float*)d_in[2];
    const float* cm1_w  = (const float*)d_in[3];
    const float* cm1_b  = (const float*)d_in[4];
    const float* ln_g   = (const float*)d_in[5];
    const float* ln_b   = (const float*)d_in[6];
    const float* cm2_w  = (const float*)d_in[7];
    const float* cm2_b  = (const float*)d_in[8];
    const float* out_w  = (const float*)d_in[9];
    const float* out_b  = (const float*)d_in[10];
    const float* att_w  = (const float*)d_in[11];
    const float* att_b  = (const float*)d_in[12];

    float* zbuf   = (float*)d_ws;          // 32 floats
    float* ctxnum = zbuf + 32;             // 32*256 floats

    hipMemsetAsync(d_ws, 0, (32 + BATCH * NCH) * sizeof(float), stream);

    spool_kernel<<<BATCH * 64, 256, 0, stream>>>(x, mask_w, mask_b, ctxnum, zbuf);

    tail_kernel<<<BATCH, 256, 0, stream>>>(ctxnum, zbuf,
                                           cm1_w, cm1_b, ln_g, ln_b,
                                           cm2_w, cm2_b, out_w, out_b,
                                           att_w, att_b, (float*)d_out);
}